// Round 16
// baseline (303.148 us; speedup 1.0000x reference)
//
#include <hip/hip_runtime.h>

#define NODES   64
#define FRAMES  4096
#define INCH    9
#define H1DIM   256
#define H2DIM   512
#define NEDGE   256
#define CHUNK   64
#define ELLW    16
#define TAILMAX 64
#define FPB     16   // frames per block -> grid = 256 = 1 block/CU

typedef _Float16 half8_t __attribute__((ext_vector_type(8)));
typedef _Float16 half4_t __attribute__((ext_vector_type(4)));
typedef float    f32x16  __attribute__((ext_vector_type(16)));

// ---------------------------------------------------------------------------
// prep: dense normalized A (row=dst, self-loops) -> Adense (global, fp32),
// ELL[64][16] + tail (for the tiny A@X only), zero acc. int32/int64 handled.
// ---------------------------------------------------------------------------
__global__ void prep_kernel(const int* __restrict__ ei,
                            float* __restrict__ acc,
                            float2* __restrict__ ellG,
                            int* __restrict__ tailCntG,
                            int* __restrict__ tailRowG,
                            int* __restrict__ tailColG,
                            float* __restrict__ tailValG,
                            float* __restrict__ AdenseG)
{
    __shared__ float sA[NODES * NODES];
    __shared__ float dis[NODES];
    __shared__ int   deg[NODES];
    __shared__ int   sTail;
    __shared__ int   flag;
    const int t = threadIdx.x;  // 256 threads
    if (t == 0) { flag = 0; sTail = 0; }
    for (int i = t; i < NODES * NODES; i += 256) sA[i] = 0.f;
    if (t < NODES) deg[t] = 1;  // self-loop
    __syncthreads();
    if (ei[2 * t + 1] != 0) atomicOr(&flag, 1);   // int64 detection
    __syncthreads();
    const bool is64 = (flag == 0);
    int s = 0, d = 0;
    if (t < NEDGE) {
        if (is64) { s = ei[2 * t];   d = ei[512 + 2 * t]; }
        else      { s = ei[t];       d = ei[NEDGE + t];   }
        atomicAdd(&deg[d], 1);
    }
    __syncthreads();
    if (t < NODES) dis[t] = rsqrtf((float)deg[t]);
    __syncthreads();
    if (t < NEDGE) atomicAdd(&sA[d * NODES + s], dis[s] * dis[d]);  // row = dst
    __syncthreads();
    if (t < NODES) sA[t * NODES + t] += dis[t] * dis[t];
    __syncthreads();
    for (int i = t; i < NODES * NODES; i += 256) AdenseG[i] = sA[i];
    if (t < NODES) {
        int j = 0;
        for (int m = 0; m < NODES; ++m) {
            float v = sA[t * NODES + m];
            if (v != 0.f) {
                if (j < ELLW) {
                    ellG[t * ELLW + j] = make_float2(v, __int_as_float(m));
                } else {
                    int idx = atomicAdd(&sTail, 1);
                    if (idx < TAILMAX) {
                        tailRowG[idx] = t; tailColG[idx] = m; tailValG[idx] = v;
                    }
                }
                ++j;
            }
        }
        for (; j < ELLW; ++j)
            ellG[t * ELLW + j] = make_float2(0.f, __int_as_float(0));
    }
    __syncthreads();
    if (t == 0) *tailCntG = (sTail < TAILMAX) ? sTail : TAILMAX;
    for (int i = t; i < H2DIM; i += 256) acc[i] = 0.f;
}

// ---------------------------------------------------------------------------
// w2frag: W2 (256x512 fp32) -> fused hi/lo B-frags [frag=kt*16+nt][lane][16].
// ---------------------------------------------------------------------------
__global__ void w2frag_kernel(const float* __restrict__ W2,
                              _Float16* __restrict__ w2f)
{
    const int frag = blockIdx.x;            // 256 frags
    const int kt = frag >> 4, nt = frag & 15;
    const int l = threadIdx.x;              // 64 threads
    const int j = nt * 32 + (l & 31);
    const int kbase = kt * 16 + (l >> 5) * 8;
    const size_t off = (size_t)frag * 1024 + (size_t)l * 16;
    #pragma unroll
    for (int jj = 0; jj < 8; ++jj) {
        float v = W2[(size_t)(kbase + jj) * H2DIM + j];
        _Float16 hv = (_Float16)v;
        w2f[off + jj]     = hv;
        w2f[off + 8 + jj] = (_Float16)(v - (float)hv);
    }
}

// ---------------------------------------------------------------------------
// w1afrag: blocks 0-7: W1 (9x256, K-padded to 16) -> B-frags [nt][lane][16];
//          blocks 8-15: Adense -> AT B-frags (hi|lo fused), lane l holds
//          AT[16kt2+8*(l>>5)+jj][32nt2+(l&31)] = A[32nt2+(l&31)][...].
// ---------------------------------------------------------------------------
__global__ void w1afrag_kernel(const float* __restrict__ W1,
                               const float* __restrict__ Adense,
                               _Float16* __restrict__ w1f,
                               _Float16* __restrict__ af)
{
    const int b = blockIdx.x;   // 16
    const int l = threadIdx.x;  // 64
    if (b < 8) {
        const size_t off = (size_t)(b * 64 + l) * 16;
        #pragma unroll
        for (int jj = 0; jj < 8; ++jj) {
            const int r = (l >> 5) * 8 + jj;
            float v = (r < INCH) ? W1[r * H1DIM + b * 32 + (l & 31)] : 0.f;
            _Float16 hv = (_Float16)v;
            w1f[off + jj]     = hv;
            w1f[off + 8 + jj] = (_Float16)(v - (float)hv);
        }
    } else {
        const int fa = b - 8;                 // nt2*4 + kt2
        const int nt2 = fa >> 2, kt2 = fa & 3;
        const size_t off = (size_t)(fa * 64 + l) * 16;
        #pragma unroll
        for (int jj = 0; jj < 8; ++jj) {
            float v = Adense[(32 * nt2 + (l & 31)) * NODES + 16 * kt2 + (l >> 5) * 8 + jj];
            _Float16 hv = (_Float16)v;
            af[off + jj]     = hv;
            af[off + 8 + jj] = (_Float16)(v - (float)hv);
        }
    }
}

// ---------------------------------------------------------------------------
// One block (1024 thr, 16 waves) per 16 FRAMES; grid = 256 = 1 block/CU.
// Frame-invariant staging (ELL/tail/ATf) + W1-frag/b1/b2 register hoist done
// ONCE; per frame (4 barriers):
//   A: AXf in-thread (ELL sum + cvt, no sAX buffer)  || issue X(fr+1) load
//   B: write X(fr+1) to sX + P1-all (3-term)  -> sH1f
//   C: P2-all (3-term, two 6-deep chains)     -> sAH1f (hi only)
//   D: G-all (16-step k-loop, 2-term) -> per-frame relu-reduce into ssum
// Epilogue once: sPart/acc atomics. Per-frame arithmetic identical to R15.
// Regs ~65 arch + 32 AGPR < 128 cap; LDS ~133 KB.
// ---------------------------------------------------------------------------
__global__ __launch_bounds__(1024, 4)
void frame_kernel(const float* __restrict__ x,
                  const float2* __restrict__ ellG,
                  const int* __restrict__ tailCntG,
                  const int* __restrict__ tailRowG,
                  const int* __restrict__ tailColG,
                  const float* __restrict__ tailValG,
                  const float* __restrict__ b1,
                  const _Float16* __restrict__ w1f,
                  const _Float16* __restrict__ af,
                  const _Float16* __restrict__ w2f,
                  const float* __restrict__ b2,
                  float* __restrict__ acc)
{
    __shared__ __align__(16) _Float16 sH1f[4][8192];   // 65536 B (hi+lo)
    __shared__ __align__(16) _Float16 sAH1f[4][4096];  // 32768 B (hi only)
    __shared__ __align__(16) _Float16 sATfH[4096];     //  8192 B
    __shared__ __align__(16) _Float16 sATfL[4096];     //  8192 B
    __shared__ __align__(16) _Float16 sAXf[2048];      //  4096 B
    __shared__ __align__(16) float2 sEll[NODES][ELLW]; //  8192 B
    __shared__ float sX[NODES][12];                    //  3072 B
    __shared__ float sPart[H2DIM];                     //  2048 B
    __shared__ int   sTR[TAILMAX];
    __shared__ int   sTC[TAILMAX];
    __shared__ float sTV[TAILMAX];
    __shared__ int   sTCnt;                            // => ~133 KB

    const int t   = threadIdx.x;
    const int f0  = blockIdx.x * FPB;
    const int wv  = t >> 6;          // 0..15
    const int ln  = t & 63;
    const int lh  = ln >> 5, l31 = ln & 31;

    // ---- one-time staging: ELL, tail, ATf, X(f0) ----
    for (int i = t; i < NODES * ELLW; i += 1024)
        sEll[i >> 4][i & 15] = ellG[i];
    if (t == 0) sTCnt = *tailCntG;
    if (t < TAILMAX) { sTR[t] = tailRowG[t]; sTC[t] = tailColG[t]; sTV[t] = tailValG[t]; }
    if (t < H2DIM) sPart[t] = 0.f;
    if (t < 512) {   // split fused af -> separate hi/lo planes
        const _Float16* ap = af + (size_t)t * 16;
        *(half8_t*)&sATfH[t * 8] = *(const half8_t*)ap;
        *(half8_t*)&sATfL[t * 8] = *(const half8_t*)(ap + 8);
    }
    if (t < NODES * INCH) {
        int n = t / INCH, c = t - n * INCH;
        sX[n][c] = x[((size_t)n * FRAMES + f0) * INCH + c];
    }

    // ---- wave-constant register hoists (frame-invariant) ----
    const int ccP = wv >> 2;                 // P1/P2 chunk
    const int mtL = (wv >> 1) & 1, ntL = wv & 1;   // P1 tile == P2 (mt2,nt2)
    const _Float16* wp = w1f + (size_t)((ccP * 2 + ntL) * 64 + ln) * 16;
    const half8_t w1h = *(const half8_t*)wp;
    const half8_t w1l = *(const half8_t*)(wp + 8);
    const float bb1 = b1[ccP * 64 + ntL * 32 + l31];
    const float bb2 = b2[wv * 32 + l31];
    const int rowA = t >> 4, colA = t & 15;  // AXf thread mapping
    const int idxA = (rowA >> 5) * 512 +
                     (((colA >> 3) << 5) | (rowA & 31)) * 8 + (colA & 7);

    float ssum = 0.f;
    __syncthreads();   // staging + X(f0) ready

    #pragma unroll 1
    for (int fr = 0; fr < FPB; ++fr) {
        // ---- A: AXf in-thread (ELL + tail + cvt) || prefetch X(fr+1) ----
        float xreg = 0.f;
        int pn = 0, pc = 0;
        const bool pf = (t < NODES * INCH) && (fr + 1 < FPB);
        if (pf) {
            pn = t / INCH; pc = t - pn * INCH;
            xreg = x[((size_t)pn * FRAMES + f0 + fr + 1) * INCH + pc];
        }
        {
            float v = 0.f;
            if (colA < INCH) {
                #pragma unroll
                for (int jx = 0; jx < ELLW; ++jx) {
                    float2 e = sEll[rowA][jx];
                    v = fmaf(e.x, sX[__float_as_int(e.y)][colA], v);
                }
                if (sTCnt > 0) {
                    #pragma unroll 1
                    for (int e = 0; e < sTCnt; ++e)
                        if (sTR[e] == rowA) v += sTV[e] * sX[sTC[e]][colA];
                }
            }
            const _Float16 hv = (_Float16)v;
            sAXf[idxA]        = hv;
            sAXf[1024 + idxA] = (_Float16)(v - (float)hv);
        }
        __syncthreads();   // bar1: sAXf ready; sX readers done

        // ---- B: write prefetched X + P1 (3-term) -> sH1f[ccP] ----
        if (pf) sX[pn][pc] = xreg;   // next read after bar4
        {
            const half8_t axh = *(const half8_t*)&sAXf[mtL * 512 + ln * 8];
            const half8_t axl = *(const half8_t*)&sAXf[1024 + mtL * 512 + ln * 8];
            f32x16 d;
            #pragma unroll
            for (int q = 0; q < 16; ++q) d[q] = 0.f;
            d = __builtin_amdgcn_mfma_f32_32x32x16_f16(axh, w1h, d, 0, 0, 0);
            d = __builtin_amdgcn_mfma_f32_32x32x16_f16(axl, w1h, d, 0, 0, 0);
            d = __builtin_amdgcn_mfma_f32_32x32x16_f16(axh, w1l, d, 0, 0, 0);
            _Float16* dst = &sH1f[ccP][0];
            #pragma unroll
            for (int j = 0; j < 4; ++j) {
                half4_t hv, lv;
                #pragma unroll
                for (int qq = 0; qq < 4; ++qq) {
                    const float v = fmaxf(d[4 * j + qq] + bb1, 0.f);
                    const _Float16 h = (_Float16)v;
                    hv[qq] = h;
                    lv[qq] = (_Float16)(v - (float)h);
                }
                const int idx = ((2 * mtL + (j >> 1)) * 2 + ntL) * 512 +
                                (((j & 1) << 5) | l31) * 8 + 4 * lh;
                *(half4_t*)&dst[idx]        = hv;
                *(half4_t*)&dst[4096 + idx] = lv;
            }
        }
        __syncthreads();   // bar2: sH1f ready

        // ---- C: P2 (3-term, two 6-deep chains) -> sAH1f[ccP] (hi only) ----
        {
            const _Float16* src = &sH1f[ccP][0];
            f32x16 d0, d1;
            #pragma unroll
            for (int q = 0; q < 16; ++q) { d0[q] = 0.f; d1[q] = 0.f; }
            #pragma unroll
            for (int kt2 = 0; kt2 < 2; ++kt2) {
                const int fb = kt2 * 2 + mtL;
                const half8_t ah = *(const half8_t*)&src[fb * 512 + ln * 8];
                const half8_t al = *(const half8_t*)&src[4096 + fb * 512 + ln * 8];
                const int fa = ntL * 4 + kt2;
                const half8_t bh = *(const half8_t*)&sATfH[fa * 512 + ln * 8];
                const half8_t bl = *(const half8_t*)&sATfL[fa * 512 + ln * 8];
                d0 = __builtin_amdgcn_mfma_f32_32x32x16_f16(ah, bh, d0, 0, 0, 0);
                d0 = __builtin_amdgcn_mfma_f32_32x32x16_f16(al, bh, d0, 0, 0, 0);
                d0 = __builtin_amdgcn_mfma_f32_32x32x16_f16(ah, bl, d0, 0, 0, 0);
            }
            #pragma unroll
            for (int kt2 = 2; kt2 < 4; ++kt2) {
                const int fb = kt2 * 2 + mtL;
                const half8_t ah = *(const half8_t*)&src[fb * 512 + ln * 8];
                const half8_t al = *(const half8_t*)&src[4096 + fb * 512 + ln * 8];
                const int fa = ntL * 4 + kt2;
                const half8_t bh = *(const half8_t*)&sATfH[fa * 512 + ln * 8];
                const half8_t bl = *(const half8_t*)&sATfL[fa * 512 + ln * 8];
                d1 = __builtin_amdgcn_mfma_f32_32x32x16_f16(ah, bh, d1, 0, 0, 0);
                d1 = __builtin_amdgcn_mfma_f32_32x32x16_f16(al, bh, d1, 0, 0, 0);
                d1 = __builtin_amdgcn_mfma_f32_32x32x16_f16(ah, bl, d1, 0, 0, 0);
            }
            d0 = d0 + d1;
            _Float16* adst = &sAH1f[ccP][0];
            #pragma unroll
            for (int j = 0; j < 4; ++j) {
                half4_t hv;
                #pragma unroll
                for (int qq = 0; qq < 4; ++qq)
                    hv[qq] = (_Float16)d0[4 * j + qq];
                const int idx = (ntL * 4 + 2 * mtL + (j >> 1)) * 512 +
                                (((j & 1) << 5) | l31) * 8 + 4 * lh;
                *(half4_t*)&adst[idx] = hv;
            }
        }
        __syncthreads();   // bar3: sAH1f ready

        // ---- D: G (16-step, 2-term) + per-frame relu-reduce ----
        {
            f32x16 a2[2];
            #pragma unroll
            for (int q = 0; q < 16; ++q) { a2[0][q] = 0.f; a2[1][q] = 0.f; }
            const _Float16* bp = w2f + (size_t)wv * 1024 + (size_t)ln * 16;
            half8_t bh = *(const half8_t*)bp;
            half8_t bl = *(const half8_t*)(bp + 8);
            #pragma unroll
            for (int ss = 0; ss < 16; ++ss) {
                const int ch = ss >> 2, s = ss & 3;
                half8_t nbh, nbl;
                if (ss < 15) {   // 1-step B prefetch
                    nbh = *(const half8_t*)(bp + 16384);
                    nbl = *(const half8_t*)(bp + 16392);
                }
                const _Float16* asrc = &sAH1f[ch][0];
                const half8_t ah0 = *(const half8_t*)&asrc[s * 512 + ln * 8];
                const half8_t ah1 = *(const half8_t*)&asrc[(4 + s) * 512 + ln * 8];
                a2[0] = __builtin_amdgcn_mfma_f32_32x32x16_f16(ah0, bh, a2[0], 0, 0, 0);
                a2[1] = __builtin_amdgcn_mfma_f32_32x32x16_f16(ah1, bh, a2[1], 0, 0, 0);
                a2[0] = __builtin_amdgcn_mfma_f32_32x32x16_f16(ah0, bl, a2[0], 0, 0, 0);
                a2[1] = __builtin_amdgcn_mfma_f32_32x32x16_f16(ah1, bl, a2[1], 0, 0, 0);
                if (ss < 15) { bh = nbh; bl = nbl; bp += 16384; }
            }
            #pragma unroll
            for (int q = 0; q < 16; ++q) {
                ssum += fmaxf(a2[0][q] + bb2, 0.f);
                ssum += fmaxf(a2[1][q] + bb2, 0.f);
            }
        }
        __syncthreads();   // bar4: G reads done; sX(fr+1) visible
    }

    // ---- epilogue (once per block): column sums -> global ----
    atomicAdd(&sPart[wv * 32 + l31], ssum);   // 2-way (lh 0/1)
    __syncthreads();
    if (t < H2DIM) atomicAdd(&acc[t], sPart[t]);
}

// ---------------------------------------------------------------------------
// head: out[c] = (acc/262144) . Wfc[:,c] + bfc[c]
// ---------------------------------------------------------------------------
__global__ void head_kernel(const float* __restrict__ acc,
                            const float* __restrict__ Wfc,
                            const float* __restrict__ bfc,
                            float* __restrict__ out)
{
    const int c = blockIdx.x * 256 + threadIdx.x;
    if (c >= H2DIM) return;
    const float scale = 1.0f / (64.0f * 4096.0f);
    float v = bfc[c];
    for (int j = 0; j < H2DIM; ++j)
        v = fmaf(acc[j] * scale, Wfc[j * H2DIM + c], v);
    out[c] = v;
}

extern "C" void kernel_launch(void* const* d_in, const int* in_sizes, int n_in,
                              void* d_out, int out_size, void* d_ws, size_t ws_size,
                              hipStream_t stream)
{
    const float* x   = (const float*)d_in[0];
    const int*   ei  = (const int*)  d_in[1];
    const float* W1  = (const float*)d_in[2];
    const float* b1  = (const float*)d_in[3];
    const float* W2  = (const float*)d_in[4];
    const float* b2  = (const float*)d_in[5];
    const float* Wfc = (const float*)d_in[6];
    const float* bfc = (const float*)d_in[7];
    float* out = (float*)d_out;

    _Float16* w2f    = (_Float16*)d_ws;              // 256K halves = 512 KB
    _Float16* w1f    = w2f + 256 * 1024;             // 8192 halves = 16 KB
    _Float16* afr    = w1f + 8192;                   // 8192 halves = 16 KB
    float*    Adense = (float*)(afr + 8192);         // 4096 f32 = 16 KB
    float*    acc    = Adense + NODES * NODES;       // 512 f32
    float2*   ell    = (float2*)(acc + H2DIM);       // 1024 float2
    int*   tailCnt   = (int*)(ell + NODES * ELLW);
    int*   tailRow   = tailCnt + 1;
    int*   tailCol   = tailRow + TAILMAX;
    float* tailVal   = (float*)(tailCol + TAILMAX);

    prep_kernel   <<<1,      256,  0, stream>>>(ei, acc, ell, tailCnt,
                                                tailRow, tailCol, tailVal, Adense);
    w2frag_kernel <<<256,     64,  0, stream>>>(W2, w2f);
    w1afrag_kernel<<<16,      64,  0, stream>>>(W1, Adense, w1f, afr);
    frame_kernel  <<<FRAMES / FPB, 1024, 0, stream>>>(x, ell, tailCnt,
                                                      tailRow, tailCol, tailVal,
                                                      b1, w1f, afr, w2f, b2, acc);
    head_kernel   <<<2,      256,  0, stream>>>(acc, Wfc, bfc, out);
}

// Round 17
// 271.099 us; speedup vs baseline: 1.1182x; 1.1182x over previous
//
#include <hip/hip_runtime.h>

#define NODES   64
#define FRAMES  4096
#define INCH    9
#define H1DIM   256
#define H2DIM   512
#define NEDGE   256
#define CHUNK   64
#define ELLW    16
#define TAILMAX 64

typedef _Float16 half8_t __attribute__((ext_vector_type(8)));
typedef _Float16 half4_t __attribute__((ext_vector_type(4)));
typedef float    f32x16  __attribute__((ext_vector_type(16)));

// ---------------------------------------------------------------------------
// prep: dense normalized A (row=dst, self-loops) -> Adense (global, fp32),
// ELL[64][16] + tail (for the tiny A@X only), zero acc. int32/int64 handled.
// ---------------------------------------------------------------------------
__global__ void prep_kernel(const int* __restrict__ ei,
                            float* __restrict__ acc,
                            float2* __restrict__ ellG,
                            int* __restrict__ tailCntG,
                            int* __restrict__ tailRowG,
                            int* __restrict__ tailColG,
                            float* __restrict__ tailValG,
                            float* __restrict__ AdenseG)
{
    __shared__ float sA[NODES * NODES];
    __shared__ float dis[NODES];
    __shared__ int   deg[NODES];
    __shared__ int   sTail;
    __shared__ int   flag;
    const int t = threadIdx.x;  // 256 threads
    if (t == 0) { flag = 0; sTail = 0; }
    for (int i = t; i < NODES * NODES; i += 256) sA[i] = 0.f;
    if (t < NODES) deg[t] = 1;  // self-loop
    __syncthreads();
    if (ei[2 * t + 1] != 0) atomicOr(&flag, 1);   // int64 detection
    __syncthreads();
    const bool is64 = (flag == 0);
    int s = 0, d = 0;
    if (t < NEDGE) {
        if (is64) { s = ei[2 * t];   d = ei[512 + 2 * t]; }
        else      { s = ei[t];       d = ei[NEDGE + t];   }
        atomicAdd(&deg[d], 1);
    }
    __syncthreads();
    if (t < NODES) dis[t] = rsqrtf((float)deg[t]);
    __syncthreads();
    if (t < NEDGE) atomicAdd(&sA[d * NODES + s], dis[s] * dis[d]);  // row = dst
    __syncthreads();
    if (t < NODES) sA[t * NODES + t] += dis[t] * dis[t];
    __syncthreads();
    for (int i = t; i < NODES * NODES; i += 256) AdenseG[i] = sA[i];
    if (t < NODES) {
        int j = 0;
        for (int m = 0; m < NODES; ++m) {
            float v = sA[t * NODES + m];
            if (v != 0.f) {
                if (j < ELLW) {
                    ellG[t * ELLW + j] = make_float2(v, __int_as_float(m));
                } else {
                    int idx = atomicAdd(&sTail, 1);
                    if (idx < TAILMAX) {
                        tailRowG[idx] = t; tailColG[idx] = m; tailValG[idx] = v;
                    }
                }
                ++j;
            }
        }
        for (; j < ELLW; ++j)
            ellG[t * ELLW + j] = make_float2(0.f, __int_as_float(0));
    }
    __syncthreads();
    if (t == 0) *tailCntG = (sTail < TAILMAX) ? sTail : TAILMAX;
    for (int i = t; i < H2DIM; i += 256) acc[i] = 0.f;
}

// ---------------------------------------------------------------------------
// w2frag: W2 (256x512 fp32) -> fused hi/lo B-frags [frag=kt*16+nt][lane][16].
// ---------------------------------------------------------------------------
__global__ void w2frag_kernel(const float* __restrict__ W2,
                              _Float16* __restrict__ w2f)
{
    const int frag = blockIdx.x;            // 256 frags
    const int kt = frag >> 4, nt = frag & 15;
    const int l = threadIdx.x;              // 64 threads
    const int j = nt * 32 + (l & 31);
    const int kbase = kt * 16 + (l >> 5) * 8;
    const size_t off = (size_t)frag * 1024 + (size_t)l * 16;
    #pragma unroll
    for (int jj = 0; jj < 8; ++jj) {
        float v = W2[(size_t)(kbase + jj) * H2DIM + j];
        _Float16 hv = (_Float16)v;
        w2f[off + jj]     = hv;
        w2f[off + 8 + jj] = (_Float16)(v - (float)hv);
    }
}

// ---------------------------------------------------------------------------
// w1afrag: blocks 0-7: W1 (9x256, K-padded to 16) -> B-frags [nt][lane][16];
//          blocks 8-15: Adense -> AT B-frags (hi|lo fused), lane l holds
//          AT[16kt2+8*(l>>5)+jj][32nt2+(l&31)] = A[32nt2+(l&31)][...].
// ---------------------------------------------------------------------------
__global__ void w1afrag_kernel(const float* __restrict__ W1,
                               const float* __restrict__ Adense,
                               _Float16* __restrict__ w1f,
                               _Float16* __restrict__ af)
{
    const int b = blockIdx.x;   // 16
    const int l = threadIdx.x;  // 64
    if (b < 8) {
        const size_t off = (size_t)(b * 64 + l) * 16;
        #pragma unroll
        for (int jj = 0; jj < 8; ++jj) {
            const int r = (l >> 5) * 8 + jj;
            float v = (r < INCH) ? W1[r * H1DIM + b * 32 + (l & 31)] : 0.f;
            _Float16 hv = (_Float16)v;
            w1f[off + jj]     = hv;
            w1f[off + 8 + jj] = (_Float16)(v - (float)hv);
        }
    } else {
        const int fa = b - 8;                 // nt2*4 + kt2
        const int nt2 = fa >> 2, kt2 = fa & 3;
        const size_t off = (size_t)(fa * 64 + l) * 16;
        #pragma unroll
        for (int jj = 0; jj < 8; ++jj) {
            float v = Adense[(32 * nt2 + (l & 31)) * NODES + 16 * kt2 + (l >> 5) * 8 + jj];
            _Float16 hv = (_Float16)v;
            af[off + jj]     = hv;
            af[off + 8 + jj] = (_Float16)(v - (float)hv);
        }
    }
}

// ---------------------------------------------------------------------------
// 8-wave (512 thr) block per (frame, N-half): grid = 2*FRAMES, 2 blocks/CU.
//   f = bid>>1, h = bid&1 (output cols h*256..h*256+255, n-tiles h*8+wv).
//   Full P1+P2 per block (duplicated across halves - cheap); G on 8 n-tiles.
//   R12 chunk-pipeline: pre P1(0); per chunk: M=[w0-3 P1(ch+1) || w4-7 P2(ch)];
//   bar; G(ch); (no trailing bar - parity dbuf). R14 numerics: P1/P2 3-term,
//   sAH1f hi-only, G 2-term.  P2's AT B-frags read directly from L2 (af).
// Regs ~55 arch + 32 AGPR = ~87 <= 128 -> 2 blocks/CU (launch_bounds(512,2),
// R3-proven). LDS ~69 KB -> 2 blocks fit (138 < 160 KB).
// ---------------------------------------------------------------------------
__global__ __launch_bounds__(512, 2)
void frame_kernel(const float* __restrict__ x,
                  const float2* __restrict__ ellG,
                  const int* __restrict__ tailCntG,
                  const int* __restrict__ tailRowG,
                  const int* __restrict__ tailColG,
                  const float* __restrict__ tailValG,
                  const float* __restrict__ b1,
                  const _Float16* __restrict__ w1f,
                  const _Float16* __restrict__ af,
                  const _Float16* __restrict__ w2f,
                  const float* __restrict__ b2,
                  float* __restrict__ acc)
{
    __shared__ __align__(16) float2 sEll[NODES][ELLW];   //  8192 B
    __shared__ float sX [NODES][12];                     //  3072 B
    __shared__ float sAX[NODES][12];                     //  3072 B
    __shared__ __align__(16) _Float16 sAXf[2048];        //  4096 B
    __shared__ __align__(16) _Float16 sH1f[2][8192];     // 32768 B (dbuf, hi+lo)
    __shared__ __align__(16) _Float16 sAH1f[2][4096];    // 16384 B (dbuf, hi only)
    __shared__ float sPart[256];                         //  1024 B
    __shared__ int   sTR[TAILMAX];
    __shared__ int   sTC[TAILMAX];
    __shared__ float sTV[TAILMAX];
    __shared__ int   sTCnt;                              // => ~69.4 KB

    const int t   = threadIdx.x;
    const int f   = blockIdx.x >> 1;
    const int h   = blockIdx.x & 1;     // N-half
    const int wv  = t >> 6;             // 0..7
    const int ln  = t & 63;
    const int lh  = ln >> 5, l31 = ln & 31;

    // ---- stage ELL, tail, X ----
    for (int i = t; i < NODES * ELLW; i += 512)
        sEll[i >> 4][i & 15] = ellG[i];
    if (t == 0) sTCnt = *tailCntG;
    if (t < TAILMAX) { sTR[t] = tailRowG[t]; sTC[t] = tailColG[t]; sTV[t] = tailValG[t]; }
    if (t < 256) sPart[t] = 0.f;
    for (int i = t; i < NODES * INCH; i += 512) {
        int n = i / INCH, c = i - n * INCH;
        sX[n][c] = x[((size_t)n * FRAMES + f) * INCH + c];
    }
    __syncthreads();

    // ---- AX = A@X via ELL (+tail), fp32 exact ----
    for (int i = t; i < NODES * INCH; i += 512) {
        int n = i / INCH, c = i - n * INCH;
        float v = 0.f;
        #pragma unroll
        for (int jx = 0; jx < ELLW; ++jx) {
            float2 e = sEll[n][jx];
            v = fmaf(e.x, sX[__float_as_int(e.y)][c], v);
        }
        sAX[n][c] = v;
    }
    if (sTCnt > 0) {
        __syncthreads();
        for (int i = t; i < sTCnt * INCH; i += 512) {
            int e = i / INCH, c = i - e * INCH;
            atomicAdd(&sAX[sTR[e]][c], sTV[e] * sX[sTC[e]][c]);
        }
    }
    __syncthreads();

    // ---- AX -> f16 hi/lo A-frags (K padded 9->16) ----
    for (int i = t; i < 1024; i += 512) {
        const int row = i >> 4, col = i & 15;
        const float v = (col < INCH) ? sAX[row][col] : 0.f;
        const _Float16 hv = (_Float16)v;
        const _Float16 lv = (_Float16)(v - (float)hv);
        const int idx = (row >> 5) * 512 +
                        (((col >> 3) << 5) | (row & 31)) * 8 + (col & 7);
        sAXf[idx]        = hv;
        sAXf[1024 + idx] = lv;
    }
    __syncthreads();

    f32x16 a2[2];
    #pragma unroll
    for (int q = 0; q < 16; ++q) { a2[0][q] = 0.f; a2[1][q] = 0.f; }

    // ---- P1: layer1 chunk cc on MFMA (callers: waves 0-3), 3-term ----
    auto P1 = [&](int cc) {
        const int mtL = wv >> 1, ntL = wv & 1;
        const half8_t axh = *(const half8_t*)&sAXf[mtL * 512 + ln * 8];
        const half8_t axl = *(const half8_t*)&sAXf[1024 + mtL * 512 + ln * 8];
        const _Float16* wp = w1f + (size_t)((cc * 2 + ntL) * 64 + ln) * 16;
        const half8_t wh = *(const half8_t*)wp;
        const half8_t wl = *(const half8_t*)(wp + 8);
        f32x16 d;
        #pragma unroll
        for (int q = 0; q < 16; ++q) d[q] = 0.f;
        d = __builtin_amdgcn_mfma_f32_32x32x16_f16(axh, wh, d, 0, 0, 0);
        d = __builtin_amdgcn_mfma_f32_32x32x16_f16(axl, wh, d, 0, 0, 0);
        d = __builtin_amdgcn_mfma_f32_32x32x16_f16(axh, wl, d, 0, 0, 0);
        const float bb = b1[cc * 64 + ntL * 32 + l31];
        _Float16* dst = &sH1f[cc & 1][0];
        #pragma unroll
        for (int j = 0; j < 4; ++j) {
            half4_t hv, lv;
            #pragma unroll
            for (int qq = 0; qq < 4; ++qq) {
                const float v = fmaxf(d[4 * j + qq] + bb, 0.f);
                const _Float16 hvv = (_Float16)v;
                hv[qq] = hvv;
                lv[qq] = (_Float16)(v - (float)hvv);
            }
            const int idx = ((2 * mtL + (j >> 1)) * 2 + ntL) * 512 +
                            (((j & 1) << 5) | l31) * 8 + 4 * lh;
            *(half4_t*)&dst[idx]        = hv;
            *(half4_t*)&dst[4096 + idx] = lv;
        }
    };

    // ---- P2: aggregation chunk cc (callers: waves 4-7), 3-term, AT frags
    //      from L2, two 6-deep chains; stores HI plane only (G is 2-term) ----
    auto P2 = [&](int cc) {
        const int ww = wv & 3;
        const int mt2 = ww >> 1;   // h1col tile
        const int nt2 = ww & 1;    // node_out tile
        const _Float16* src = &sH1f[cc & 1][0];
        f32x16 d0, d1;
        #pragma unroll
        for (int q = 0; q < 16; ++q) { d0[q] = 0.f; d1[q] = 0.f; }
        #pragma unroll
        for (int kt2 = 0; kt2 < 2; ++kt2) {
            const int fb = kt2 * 2 + mt2;
            const half8_t ah = *(const half8_t*)&src[fb * 512 + ln * 8];
            const half8_t al = *(const half8_t*)&src[4096 + fb * 512 + ln * 8];
            const _Float16* ap = af + (size_t)((nt2 * 4 + kt2) * 64 + ln) * 16;
            const half8_t bh = *(const half8_t*)ap;          // L2-resident
            const half8_t bl = *(const half8_t*)(ap + 8);
            d0 = __builtin_amdgcn_mfma_f32_32x32x16_f16(ah, bh, d0, 0, 0, 0);
            d0 = __builtin_amdgcn_mfma_f32_32x32x16_f16(al, bh, d0, 0, 0, 0);
            d0 = __builtin_amdgcn_mfma_f32_32x32x16_f16(ah, bl, d0, 0, 0, 0);
        }
        #pragma unroll
        for (int kt2 = 2; kt2 < 4; ++kt2) {
            const int fb = kt2 * 2 + mt2;
            const half8_t ah = *(const half8_t*)&src[fb * 512 + ln * 8];
            const half8_t al = *(const half8_t*)&src[4096 + fb * 512 + ln * 8];
            const _Float16* ap = af + (size_t)((nt2 * 4 + kt2) * 64 + ln) * 16;
            const half8_t bh = *(const half8_t*)ap;
            const half8_t bl = *(const half8_t*)(ap + 8);
            d1 = __builtin_amdgcn_mfma_f32_32x32x16_f16(ah, bh, d1, 0, 0, 0);
            d1 = __builtin_amdgcn_mfma_f32_32x32x16_f16(al, bh, d1, 0, 0, 0);
            d1 = __builtin_amdgcn_mfma_f32_32x32x16_f16(ah, bl, d1, 0, 0, 0);
        }
        d0 = d0 + d1;
        // D: col(lane)=node_out, row(reg)=h1col -> A-frag store (hi only)
        _Float16* adst = &sAH1f[cc & 1][0];
        #pragma unroll
        for (int j = 0; j < 4; ++j) {
            half4_t hv;
            #pragma unroll
            for (int qq = 0; qq < 4; ++qq)
                hv[qq] = (_Float16)d0[4 * j + qq];
            const int idx = (nt2 * 4 + 2 * mt2 + (j >> 1)) * 512 +
                            (((j & 1) << 5) | l31) * 8 + 4 * lh;
            *(half4_t*)&adst[idx] = hv;
        }
    };

    // ---- pre-phase: P1(0) ----
    if (wv < 4) P1(0);
    __syncthreads();

    const int nt = h * 8 + wv;   // this wave's n-tile (G)

    #pragma unroll 1
    for (int ch = 0; ch < 4; ++ch) {
        // ---- M phase: P1(ch+1) (waves 0-3) || P2(ch) (waves 4-7) ----
        if (wv < 4) {
            if (ch < 3) P1(ch + 1);
        } else {
            P2(ch);
        }
        __syncthreads();   // the ONLY barrier per chunk

        // ---- G phase: P3(ch), wave = n-tile nt, both m-tiles, 2-term ----
        {
            const _Float16* asrc = &sAH1f[ch & 1][0];
            const _Float16* bp = w2f +
                ((size_t)(ch * 4) * 16 + nt) * 1024 + (size_t)ln * 16;
            half8_t bh = *(const half8_t*)bp;
            half8_t bl = *(const half8_t*)(bp + 8);
            #pragma unroll
            for (int s = 0; s < 4; ++s) {
                half8_t nbh, nbl;
                if (s < 3) {   // prefetch next k-group's B frags (16 KB stride)
                    nbh = *(const half8_t*)(bp + 16384);
                    nbl = *(const half8_t*)(bp + 16392);
                }
                const half8_t ah0 = *(const half8_t*)&asrc[s * 512 + ln * 8];
                const half8_t ah1 = *(const half8_t*)&asrc[(4 + s) * 512 + ln * 8];
                a2[0] = __builtin_amdgcn_mfma_f32_32x32x16_f16(ah0, bh, a2[0], 0, 0, 0);
                a2[1] = __builtin_amdgcn_mfma_f32_32x32x16_f16(ah1, bh, a2[1], 0, 0, 0);
                a2[0] = __builtin_amdgcn_mfma_f32_32x32x16_f16(ah0, bl, a2[0], 0, 0, 0);
                a2[1] = __builtin_amdgcn_mfma_f32_32x32x16_f16(ah1, bl, a2[1], 0, 0, 0);
                if (s < 3) { bh = nbh; bl = nbl; bp += 16384; }
            }
        }
        // no trailing barrier: next M writes only opposite-parity buffers;
        // the next chunk's single barrier orders everything else.
    }

    // ---- epilogue: relu + bias, column sums into half-local sPart ----
    {
        const float bb = b2[nt * 32 + l31];
        float ssum = 0.f;
        #pragma unroll
        for (int q = 0; q < 16; ++q) {
            ssum += fmaxf(a2[0][q] + bb, 0.f);   // nodes tile 0
            ssum += fmaxf(a2[1][q] + bb, 0.f);   // nodes tile 1
        }
        atomicAdd(&sPart[wv * 32 + l31], ssum);  // 2-way (lh 0/1)
    }
    __syncthreads();
    if (t < 256) atomicAdd(&acc[h * 256 + t], sPart[t]);
}

// ---------------------------------------------------------------------------
// head: out[c] = (acc/262144) . Wfc[:,c] + bfc[c]
// ---------------------------------------------------------------------------
__global__ void head_kernel(const float* __restrict__ acc,
                            const float* __restrict__ Wfc,
                            const float* __restrict__ bfc,
                            float* __restrict__ out)
{
    const int c = blockIdx.x * 256 + threadIdx.x;
    if (c >= H2DIM) return;
    const float scale = 1.0f / (64.0f * 4096.0f);
    float v = bfc[c];
    for (int j = 0; j < H2DIM; ++j)
        v = fmaf(acc[j] * scale, Wfc[j * H2DIM + c], v);
    out[c] = v;
}

extern "C" void kernel_launch(void* const* d_in, const int* in_sizes, int n_in,
                              void* d_out, int out_size, void* d_ws, size_t ws_size,
                              hipStream_t stream)
{
    const float* x   = (const float*)d_in[0];
    const int*   ei  = (const int*)  d_in[1];
    const float* W1  = (const float*)d_in[2];
    const float* b1  = (const float*)d_in[3];
    const float* W2  = (const float*)d_in[4];
    const float* b2  = (const float*)d_in[5];
    const float* Wfc = (const float*)d_in[6];
    const float* bfc = (const float*)d_in[7];
    float* out = (float*)d_out;

    _Float16* w2f    = (_Float16*)d_ws;              // 256K halves = 512 KB
    _Float16* w1f    = w2f + 256 * 1024;             // 8192 halves = 16 KB
    _Float16* afr    = w1f + 8192;                   // 8192 halves = 16 KB
    float*    Adense = (float*)(afr + 8192);         // 4096 f32 = 16 KB
    float*    acc    = Adense + NODES * NODES;       // 512 f32
    float2*   ell    = (float2*)(acc + H2DIM);       // 1024 float2
    int*   tailCnt   = (int*)(ell + NODES * ELLW);
    int*   tailRow   = tailCnt + 1;
    int*   tailCol   = tailRow + TAILMAX;
    float* tailVal   = (float*)(tailCol + TAILMAX);

    prep_kernel   <<<1,          256, 0, stream>>>(ei, acc, ell, tailCnt,
                                                   tailRow, tailCol, tailVal, Adense);
    w2frag_kernel <<<256,         64, 0, stream>>>(W2, w2f);
    w1afrag_kernel<<<16,          64, 0, stream>>>(W1, Adense, w1f, afr);
    frame_kernel  <<<FRAMES * 2, 512, 0, stream>>>(x, ell, tailCnt,
                                                   tailRow, tailCol, tailVal,
                                                   b1, w1f, afr, w2f, b2, acc);
    head_kernel   <<<2,          256, 0, stream>>>(acc, Wfc, bfc, out);
}

// Round 18
// 199.742 us; speedup vs baseline: 1.5177x; 1.3572x over previous
//
#include <hip/hip_runtime.h>

#define NODES   64
#define FRAMES  4096
#define INCH    9
#define H1DIM   256
#define H2DIM   512
#define NEDGE   256
#define CHUNK   64
#define ELLW    16
#define TAILMAX 64

typedef _Float16 half8_t __attribute__((ext_vector_type(8)));
typedef _Float16 half4_t __attribute__((ext_vector_type(4)));
typedef float    f32x16  __attribute__((ext_vector_type(16)));

// ---------------------------------------------------------------------------
// prep: dense normalized A (row=dst, self-loops) -> Adense (global, fp32),
// ELL[64][16] + tail (for the tiny A@X only), zero acc. int32/int64 handled.
// ---------------------------------------------------------------------------
__global__ void prep_kernel(const int* __restrict__ ei,
                            float* __restrict__ acc,
                            float2* __restrict__ ellG,
                            int* __restrict__ tailCntG,
                            int* __restrict__ tailRowG,
                            int* __restrict__ tailColG,
                            float* __restrict__ tailValG,
                            float* __restrict__ AdenseG)
{
    __shared__ float sA[NODES * NODES];
    __shared__ float dis[NODES];
    __shared__ int   deg[NODES];
    __shared__ int   sTail;
    __shared__ int   flag;
    const int t = threadIdx.x;  // 256 threads
    if (t == 0) { flag = 0; sTail = 0; }
    for (int i = t; i < NODES * NODES; i += 256) sA[i] = 0.f;
    if (t < NODES) deg[t] = 1;  // self-loop
    __syncthreads();
    if (ei[2 * t + 1] != 0) atomicOr(&flag, 1);   // int64 detection
    __syncthreads();
    const bool is64 = (flag == 0);
    int s = 0, d = 0;
    if (t < NEDGE) {
        if (is64) { s = ei[2 * t];   d = ei[512 + 2 * t]; }
        else      { s = ei[t];       d = ei[NEDGE + t];   }
        atomicAdd(&deg[d], 1);
    }
    __syncthreads();
    if (t < NODES) dis[t] = rsqrtf((float)deg[t]);
    __syncthreads();
    if (t < NEDGE) atomicAdd(&sA[d * NODES + s], dis[s] * dis[d]);  // row = dst
    __syncthreads();
    if (t < NODES) sA[t * NODES + t] += dis[t] * dis[t];
    __syncthreads();
    for (int i = t; i < NODES * NODES; i += 256) AdenseG[i] = sA[i];
    if (t < NODES) {
        int j = 0;
        for (int m = 0; m < NODES; ++m) {
            float v = sA[t * NODES + m];
            if (v != 0.f) {
                if (j < ELLW) {
                    ellG[t * ELLW + j] = make_float2(v, __int_as_float(m));
                } else {
                    int idx = atomicAdd(&sTail, 1);
                    if (idx < TAILMAX) {
                        tailRowG[idx] = t; tailColG[idx] = m; tailValG[idx] = v;
                    }
                }
                ++j;
            }
        }
        for (; j < ELLW; ++j)
            ellG[t * ELLW + j] = make_float2(0.f, __int_as_float(0));
    }
    __syncthreads();
    if (t == 0) *tailCntG = (sTail < TAILMAX) ? sTail : TAILMAX;
    for (int i = t; i < H2DIM; i += 256) acc[i] = 0.f;
}

// ---------------------------------------------------------------------------
// w2frag: W2 (256x512 fp32) -> fused hi/lo B-frags [frag=kt*16+nt][lane][16].
// ---------------------------------------------------------------------------
__global__ void w2frag_kernel(const float* __restrict__ W2,
                              _Float16* __restrict__ w2f)
{
    const int frag = blockIdx.x;            // 256 frags
    const int kt = frag >> 4, nt = frag & 15;
    const int l = threadIdx.x;              // 64 threads
    const int j = nt * 32 + (l & 31);
    const int kbase = kt * 16 + (l >> 5) * 8;
    const size_t off = (size_t)frag * 1024 + (size_t)l * 16;
    #pragma unroll
    for (int jj = 0; jj < 8; ++jj) {
        float v = W2[(size_t)(kbase + jj) * H2DIM + j];
        _Float16 hv = (_Float16)v;
        w2f[off + jj]     = hv;
        w2f[off + 8 + jj] = (_Float16)(v - (float)hv);
    }
}

// ---------------------------------------------------------------------------
// w1afrag: blocks 0-7: W1 (9x256, K-padded to 16) -> B-frags [nt][lane][16];
//          blocks 8-15: Adense -> AT B-frags (hi|lo fused), lane l holds
//          AT[16kt2+8*(l>>5)+jj][32nt2+(l&31)] = A[32nt2+(l&31)][...].
// ---------------------------------------------------------------------------
__global__ void w1afrag_kernel(const float* __restrict__ W1,
                               const float* __restrict__ Adense,
                               _Float16* __restrict__ w1f,
                               _Float16* __restrict__ af)
{
    const int b = blockIdx.x;   // 16
    const int l = threadIdx.x;  // 64
    if (b < 8) {
        const size_t off = (size_t)(b * 64 + l) * 16;
        #pragma unroll
        for (int jj = 0; jj < 8; ++jj) {
            const int r = (l >> 5) * 8 + jj;
            float v = (r < INCH) ? W1[r * H1DIM + b * 32 + (l & 31)] : 0.f;
            _Float16 hv = (_Float16)v;
            w1f[off + jj]     = hv;
            w1f[off + 8 + jj] = (_Float16)(v - (float)hv);
        }
    } else {
        const int fa = b - 8;                 // nt2*4 + kt2
        const int nt2 = fa >> 2, kt2 = fa & 3;
        const size_t off = (size_t)(fa * 64 + l) * 16;
        #pragma unroll
        for (int jj = 0; jj < 8; ++jj) {
            float v = Adense[(32 * nt2 + (l & 31)) * NODES + 16 * kt2 + (l >> 5) * 8 + jj];
            _Float16 hv = (_Float16)v;
            af[off + jj]     = hv;
            af[off + 8 + jj] = (_Float16)(v - (float)hv);
        }
    }
}

// ---------------------------------------------------------------------------
// One block (1024 thr, 16 waves) per FRAME PAIR; grid = 2048.
// G processes BOTH frames per w2f B-read -> B L2-traffic per frame halves
// (the dominant R15 cost: 512 KB/frame at ~56 B/cyc/CU = 9.1K cyc).
//   phases: stage(X x2) | AX x2 | AXf x2 | P1(f0) | P2(f0) | P1(f1) | P2(f1)
//           | G(pair, 16 steps x 8 MFMA) | epilogue
// Numerics: P1 3-term; H1 stored HI-ONLY (new drop: data-dependent rounding,
// same class as R14's accepted A-lo drop); P2 2-term (ah x AThi/ATlo);
// G 2-term (AH1hi x W2hi/W2lo). a2[frame][m] = 64 AGPR + ~50 arch < 128 cap.
// LDS ~143 KB -> 1 block/CU.
// ---------------------------------------------------------------------------
__global__ __launch_bounds__(1024, 4)
void frame_kernel(const float* __restrict__ x,
                  const float2* __restrict__ ellG,
                  const int* __restrict__ tailCntG,
                  const int* __restrict__ tailRowG,
                  const int* __restrict__ tailColG,
                  const float* __restrict__ tailValG,
                  const float* __restrict__ b1,
                  const _Float16* __restrict__ w1f,
                  const _Float16* __restrict__ af,
                  const _Float16* __restrict__ w2f,
                  const float* __restrict__ b2,
                  float* __restrict__ acc)
{
    __shared__ __align__(16) float2 sEll[NODES][ELLW];    //  8192 B
    __shared__ float sX [2][NODES][12];                   //  6144 B
    __shared__ float sAX[2][NODES][12];                   //  6144 B
    __shared__ __align__(16) _Float16 sAXf[2][2048];      //  8192 B (hi+lo)
    __shared__ __align__(16) _Float16 sH1f[4][4096];      // 32768 B (HI only)
    __shared__ __align__(16) _Float16 sAH1f[2][4][4096];  // 65536 B (hi only)
    __shared__ __align__(16) _Float16 sATfH[4096];        //  8192 B
    __shared__ __align__(16) _Float16 sATfL[4096];        //  8192 B
    __shared__ float sPart[H2DIM];                        //  2048 B
    __shared__ int   sTR[TAILMAX];
    __shared__ int   sTC[TAILMAX];
    __shared__ float sTV[TAILMAX];
    __shared__ int   sTCnt;                               // => ~143 KB

    const int t   = threadIdx.x;
    const int f0  = blockIdx.x * 2;
    const int wv  = t >> 6;          // 0..15
    const int ln  = t & 63;
    const int lh  = ln >> 5, l31 = ln & 31;

    // ---- stage ELL, tail, ATf, X(f0), X(f0+1) ----
    for (int i = t; i < NODES * ELLW; i += 1024)
        sEll[i >> 4][i & 15] = ellG[i];
    if (t == 0) sTCnt = *tailCntG;
    if (t < TAILMAX) { sTR[t] = tailRowG[t]; sTC[t] = tailColG[t]; sTV[t] = tailValG[t]; }
    if (t < H2DIM) sPart[t] = 0.f;
    if (t < 512) {   // split fused af -> separate hi/lo planes
        const _Float16* ap = af + (size_t)t * 16;
        *(half8_t*)&sATfH[t * 8] = *(const half8_t*)ap;
        *(half8_t*)&sATfL[t * 8] = *(const half8_t*)(ap + 8);
    }
    for (int i = t; i < 2 * NODES * INCH; i += 1024) {
        const int ff = i / (NODES * INCH);
        const int r  = i - ff * (NODES * INCH);
        const int n  = r / INCH, c = r - n * INCH;
        sX[ff][n][c] = x[((size_t)n * FRAMES + f0 + ff) * INCH + c];
    }
    __syncthreads();

    // ---- AX = A@X via ELL (+tail), fp32 exact, both frames ----
    for (int i = t; i < 2 * NODES * INCH; i += 1024) {
        const int ff = i / (NODES * INCH);
        const int r  = i - ff * (NODES * INCH);
        const int n  = r / INCH, c = r - n * INCH;
        float v = 0.f;
        #pragma unroll
        for (int jx = 0; jx < ELLW; ++jx) {
            float2 e = sEll[n][jx];
            v = fmaf(e.x, sX[ff][__float_as_int(e.y)][c], v);
        }
        sAX[ff][n][c] = v;
    }
    if (sTCnt > 0) {
        __syncthreads();
        for (int i = t; i < 2 * sTCnt * INCH; i += 1024) {
            const int ff = i / (sTCnt * INCH);
            const int r  = i - ff * (sTCnt * INCH);
            const int e  = r / INCH, c = r - e * INCH;
            atomicAdd(&sAX[ff][sTR[e]][c], sTV[e] * sX[ff][sTC[e]][c]);
        }
    }
    __syncthreads();

    // ---- AX -> f16 hi/lo A-frags (K padded 9->16), both frames ----
    for (int i = t; i < 2048; i += 1024) {
        const int ff  = i >> 10;
        const int ii  = i & 1023;
        const int row = ii >> 4, col = ii & 15;
        const float v = (col < INCH) ? sAX[ff][row][col] : 0.f;
        const _Float16 hv = (_Float16)v;
        const _Float16 lv = (_Float16)(v - (float)hv);
        const int idx = (row >> 5) * 512 +
                        (((col >> 3) << 5) | (row & 31)) * 8 + (col & 7);
        sAXf[ff][idx]        = hv;
        sAXf[ff][1024 + idx] = lv;
    }
    __syncthreads();

    // ---- P1: layer1 for frame ff (all 16 waves), 3-term, HI-only store ----
    auto P1 = [&](int ff) {
        const int cc  = wv >> 2;
        const int mtL = (wv >> 1) & 1, ntL = wv & 1;
        const half8_t axh = *(const half8_t*)&sAXf[ff][mtL * 512 + ln * 8];
        const half8_t axl = *(const half8_t*)&sAXf[ff][1024 + mtL * 512 + ln * 8];
        const _Float16* wp = w1f + (size_t)((cc * 2 + ntL) * 64 + ln) * 16;
        const half8_t wh = *(const half8_t*)wp;
        const half8_t wl = *(const half8_t*)(wp + 8);
        f32x16 d;
        #pragma unroll
        for (int q = 0; q < 16; ++q) d[q] = 0.f;
        d = __builtin_amdgcn_mfma_f32_32x32x16_f16(axh, wh, d, 0, 0, 0);
        d = __builtin_amdgcn_mfma_f32_32x32x16_f16(axl, wh, d, 0, 0, 0);
        d = __builtin_amdgcn_mfma_f32_32x32x16_f16(axh, wl, d, 0, 0, 0);
        const float bb = b1[cc * 64 + ntL * 32 + l31];
        _Float16* dst = &sH1f[cc][0];
        #pragma unroll
        for (int j = 0; j < 4; ++j) {
            half4_t hv;
            #pragma unroll
            for (int qq = 0; qq < 4; ++qq)
                hv[qq] = (_Float16)fmaxf(d[4 * j + qq] + bb, 0.f);
            const int idx = ((2 * mtL + (j >> 1)) * 2 + ntL) * 512 +
                            (((j & 1) << 5) | l31) * 8 + 4 * lh;
            *(half4_t*)&dst[idx] = hv;
        }
    };

    // ---- P2: aggregation for frame ff (all 16 waves), 2-term (AT hi/lo),
    //      two 4-deep chains; stores HI plane ----
    auto P2 = [&](int ff) {
        const int cc  = wv >> 2;
        const int mt2 = (wv >> 1) & 1, nt2 = wv & 1;
        const _Float16* src = &sH1f[cc][0];
        f32x16 d0, d1;
        #pragma unroll
        for (int q = 0; q < 16; ++q) { d0[q] = 0.f; d1[q] = 0.f; }
        #pragma unroll
        for (int kt2 = 0; kt2 < 2; ++kt2) {
            const int fb = kt2 * 2 + mt2;
            const half8_t ah = *(const half8_t*)&src[fb * 512 + ln * 8];
            const int fa = nt2 * 4 + kt2;
            const half8_t bh = *(const half8_t*)&sATfH[fa * 512 + ln * 8];
            const half8_t bl = *(const half8_t*)&sATfL[fa * 512 + ln * 8];
            d0 = __builtin_amdgcn_mfma_f32_32x32x16_f16(ah, bh, d0, 0, 0, 0);
            d0 = __builtin_amdgcn_mfma_f32_32x32x16_f16(ah, bl, d0, 0, 0, 0);
        }
        #pragma unroll
        for (int kt2 = 2; kt2 < 4; ++kt2) {
            const int fb = kt2 * 2 + mt2;
            const half8_t ah = *(const half8_t*)&src[fb * 512 + ln * 8];
            const int fa = nt2 * 4 + kt2;
            const half8_t bh = *(const half8_t*)&sATfH[fa * 512 + ln * 8];
            const half8_t bl = *(const half8_t*)&sATfL[fa * 512 + ln * 8];
            d1 = __builtin_amdgcn_mfma_f32_32x32x16_f16(ah, bh, d1, 0, 0, 0);
            d1 = __builtin_amdgcn_mfma_f32_32x32x16_f16(ah, bl, d1, 0, 0, 0);
        }
        d0 = d0 + d1;
        _Float16* adst = &sAH1f[ff][cc][0];
        #pragma unroll
        for (int j = 0; j < 4; ++j) {
            half4_t hv;
            #pragma unroll
            for (int qq = 0; qq < 4; ++qq)
                hv[qq] = (_Float16)d0[4 * j + qq];
            const int idx = (nt2 * 4 + 2 * mt2 + (j >> 1)) * 512 +
                            (((j & 1) << 5) | l31) * 8 + 4 * lh;
            *(half4_t*)&adst[idx] = hv;
        }
    };

    P1(0);
    __syncthreads();
    P2(0);
    __syncthreads();
    P1(1);
    __syncthreads();
    P2(1);
    __syncthreads();

    // ---- G: both frames per B-read; wave = n-tile nt=wv; 16 steps ----
    f32x16 a2[2][2];   // [frame][m-tile]
    #pragma unroll
    for (int q = 0; q < 16; ++q) {
        a2[0][0][q] = 0.f; a2[0][1][q] = 0.f;
        a2[1][0][q] = 0.f; a2[1][1][q] = 0.f;
    }
    {
        const _Float16* bp = w2f + (size_t)wv * 1024 + (size_t)ln * 16;
        half8_t bh = *(const half8_t*)bp;
        half8_t bl = *(const half8_t*)(bp + 8);
        #pragma unroll
        for (int ss = 0; ss < 16; ++ss) {
            const int ch = ss >> 2, s = ss & 3;
            half8_t nbh, nbl;
            if (ss < 15) {   // 1-step B prefetch (next k-frag row, +16 frags)
                nbh = *(const half8_t*)(bp + 16384);
                nbl = *(const half8_t*)(bp + 16392);
            }
            const _Float16* a0 = &sAH1f[0][ch][0];
            const _Float16* a1 = &sAH1f[1][ch][0];
            const half8_t f0m0 = *(const half8_t*)&a0[s * 512 + ln * 8];
            const half8_t f0m1 = *(const half8_t*)&a0[(4 + s) * 512 + ln * 8];
            const half8_t f1m0 = *(const half8_t*)&a1[s * 512 + ln * 8];
            const half8_t f1m1 = *(const half8_t*)&a1[(4 + s) * 512 + ln * 8];
            a2[0][0] = __builtin_amdgcn_mfma_f32_32x32x16_f16(f0m0, bh, a2[0][0], 0, 0, 0);
            a2[0][1] = __builtin_amdgcn_mfma_f32_32x32x16_f16(f0m1, bh, a2[0][1], 0, 0, 0);
            a2[1][0] = __builtin_amdgcn_mfma_f32_32x32x16_f16(f1m0, bh, a2[1][0], 0, 0, 0);
            a2[1][1] = __builtin_amdgcn_mfma_f32_32x32x16_f16(f1m1, bh, a2[1][1], 0, 0, 0);
            a2[0][0] = __builtin_amdgcn_mfma_f32_32x32x16_f16(f0m0, bl, a2[0][0], 0, 0, 0);
            a2[0][1] = __builtin_amdgcn_mfma_f32_32x32x16_f16(f0m1, bl, a2[0][1], 0, 0, 0);
            a2[1][0] = __builtin_amdgcn_mfma_f32_32x32x16_f16(f1m0, bl, a2[1][0], 0, 0, 0);
            a2[1][1] = __builtin_amdgcn_mfma_f32_32x32x16_f16(f1m1, bl, a2[1][1], 0, 0, 0);
            if (ss < 15) { bh = nbh; bl = nbl; bp += 16384; }
        }
    }

    // ---- epilogue: relu + bias, both frames summed (mean is over frames) ----
    {
        const float bb = b2[wv * 32 + l31];
        float ssum = 0.f;
        #pragma unroll
        for (int q = 0; q < 16; ++q) {
            ssum += fmaxf(a2[0][0][q] + bb, 0.f);
            ssum += fmaxf(a2[0][1][q] + bb, 0.f);
            ssum += fmaxf(a2[1][0][q] + bb, 0.f);
            ssum += fmaxf(a2[1][1][q] + bb, 0.f);
        }
        atomicAdd(&sPart[wv * 32 + l31], ssum);   // 2-way (lh 0/1)
    }
    __syncthreads();
    if (t < H2DIM) atomicAdd(&acc[t], sPart[t]);
}

// ---------------------------------------------------------------------------
// head: out[c] = (acc/262144) . Wfc[:,c] + bfc[c]
// ---------------------------------------------------------------------------
__global__ void head_kernel(const float* __restrict__ acc,
                            const float* __restrict__ Wfc,
                            const float* __restrict__ bfc,
                            float* __restrict__ out)
{
    const int c = blockIdx.x * 256 + threadIdx.x;
    if (c >= H2DIM) return;
    const float scale = 1.0f / (64.0f * 4096.0f);
    float v = bfc[c];
    for (int j = 0; j < H2DIM; ++j)
        v = fmaf(acc[j] * scale, Wfc[j * H2DIM + c], v);
    out[c] = v;
}

extern "C" void kernel_launch(void* const* d_in, const int* in_sizes, int n_in,
                              void* d_out, int out_size, void* d_ws, size_t ws_size,
                              hipStream_t stream)
{
    const float* x   = (const float*)d_in[0];
    const int*   ei  = (const int*)  d_in[1];
    const float* W1  = (const float*)d_in[2];
    const float* b1  = (const float*)d_in[3];
    const float* W2  = (const float*)d_in[4];
    const float* b2  = (const float*)d_in[5];
    const float* Wfc = (const float*)d_in[6];
    const float* bfc = (const float*)d_in[7];
    float* out = (float*)d_out;

    _Float16* w2f    = (_Float16*)d_ws;              // 256K halves = 512 KB
    _Float16* w1f    = w2f + 256 * 1024;             // 8192 halves = 16 KB
    _Float16* afr    = w1f + 8192;                   // 8192 halves = 16 KB
    float*    Adense = (float*)(afr + 8192);         // 4096 f32 = 16 KB
    float*    acc    = Adense + NODES * NODES;       // 512 f32
    float2*   ell    = (float2*)(acc + H2DIM);       // 1024 float2
    int*   tailCnt   = (int*)(ell + NODES * ELLW);
    int*   tailRow   = tailCnt + 1;
    int*   tailCol   = tailRow + TAILMAX;
    float* tailVal   = (float*)(tailCol + TAILMAX);

    prep_kernel   <<<1,           256,  0, stream>>>(ei, acc, ell, tailCnt,
                                                     tailRow, tailCol, tailVal, Adense);
    w2frag_kernel <<<256,          64,  0, stream>>>(W2, w2f);
    w1afrag_kernel<<<16,           64,  0, stream>>>(W1, Adense, w1f, afr);
    frame_kernel  <<<FRAMES / 2, 1024,  0, stream>>>(x, ell, tailCnt,
                                                     tailRow, tailCol, tailVal,
                                                     b1, w1f, afr, w2f, b2, acc);
    head_kernel   <<<2,           256,  0, stream>>>(acc, Wfc, bfc, out);
}